// Round 6
// baseline (206.924 us; speedup 1.0000x reference)
//
#include <hip/hip_runtime.h>
#include <stdint.h>

typedef unsigned short u16;
typedef __attribute__((ext_vector_type(8))) short bf16x8;
typedef __attribute__((ext_vector_type(4))) short s16x4;
typedef __attribute__((ext_vector_type(4))) float f32x4;

// ---- bf16 helpers (manual RNE; no hip_bf16.h dependency) ----
__device__ __forceinline__ u16 f2bf(float f) {
  uint32_t x = __builtin_bit_cast(uint32_t, f);
  uint32_t r = (x + 0x7fffu + ((x >> 16) & 1u)) >> 16;
  return (u16)r;
}
__device__ __forceinline__ float bf2f(u16 u) {
  return __builtin_bit_cast(float, (uint32_t)u << 16);
}

// ---- async global -> LDS, 16B per lane ----
typedef __attribute__((address_space(3))) uint32_t lds_u32;
typedef const __attribute__((address_space(1))) uint32_t glb_u32;
__device__ __forceinline__ void gload_lds16(const void* g, void* l) {
  __builtin_amdgcn_global_load_lds(
      reinterpret_cast<glb_u32*>(reinterpret_cast<uintptr_t>(g)),
      reinterpret_cast<lds_u32*>(reinterpret_cast<uintptr_t>(l)),
      16, 0, 0);
}

// =====================================================================
// convert f32 -> bf16 (hi), optional residual (lo). 4 elems / thread.
// =====================================================================
__global__ void cvt_split_kernel(const float* __restrict__ in, u16* __restrict__ hi,
                                 u16* __restrict__ lo, int n4) {
  typedef __attribute__((ext_vector_type(4))) float float4v;
  int i = blockIdx.x * 256 + threadIdx.x;
  const int stride = gridDim.x * 256;
  for (; i < n4; i += stride) {
    float4v v = *(const float4v*)(in + (size_t)i * 4);
    s16x4 hv;
#pragma unroll
    for (int j = 0; j < 4; ++j) hv[j] = (short)f2bf(v[j]);
    *(s16x4*)(hi + (size_t)i * 4) = hv;
    if (lo) {
      s16x4 lv;
#pragma unroll
      for (int j = 0; j < 4; ++j) lv[j] = (short)f2bf(v[j] - bf2f((u16)hv[j]));
      *(s16x4*)(lo + (size_t)i * 4) = lv;
    }
  }
}

// =====================================================================
// GEMM: C[M,N] = A[M,K] * B[N,K]^T + bias
// 128x128 tile, BK=32, 4 waves (2x2), mfma 16x16x32 bf16.
// Block remap: each XCD (orig%8) owns a contiguous strip of 16 row-
// blocks x all col-blocks, COLUMN-fast, so the 18 (or 6) blocks sharing
// an A-panel co-run on one XCD and the panel stays L2-resident.
// (R4 showed the row-fast variant of this swizzle separates A-panel
// uses in time: FETCH 83->230 MB. R5 natural order: uses 128 slots
// apart, FETCH 52.7 MB. This makes them adjacent.)
// =====================================================================
template <int OUTF32>
__global__ __launch_bounds__(256, 2) void gemm_bt(
    const u16* __restrict__ A, const u16* __restrict__ B0,
    const float* __restrict__ bias, float* __restrict__ outF, u16* __restrict__ outB,
    int Ndim, int Kdim) {
  __shared__ u16 sA[128 * 32];
  __shared__ u16 sB0[128 * 32];

  const int tid = threadIdx.x;
  const int lane = tid & 63;
  const int wr = (tid >> 6) >> 1;
  const int wc = (tid >> 6) & 1;

  const int ncols = Ndim >> 7;
  const int orig = blockIdx.y * gridDim.x + blockIdx.x;
  const int xcd = orig & 7;
  const int j = orig >> 3;  // local index within XCD strip, col-fast
  const int brow = (xcd * (gridDim.x >> 3) + j / ncols) * 128;
  const int bcol = (j % ncols) * 128;

  f32x4 acc[4][4] = {};

  for (int k0 = 0; k0 < Kdim; k0 += 32) {
    __syncthreads();
#pragma unroll
    for (int jj = 0; jj < 2; ++jj) {
      const int c = jj * 256 + tid;
      const int row = c >> 2;
      const int off = (c & 3) * 8;
      gload_lds16(A + (size_t)(brow + row) * Kdim + k0 + off, &sA[c * 8]);
      gload_lds16(B0 + (size_t)(bcol + row) * Kdim + k0 + off, &sB0[c * 8]);
    }
    __syncthreads();

    bf16x8 a[4], b[4];
#pragma unroll
    for (int m = 0; m < 4; ++m)
      a[m] = *(const bf16x8*)&sA[(wr * 64 + m * 16 + (lane & 15)) * 32 + (lane >> 4) * 8];
#pragma unroll
    for (int n = 0; n < 4; ++n)
      b[n] = *(const bf16x8*)&sB0[(wc * 64 + n * 16 + (lane & 15)) * 32 + (lane >> 4) * 8];
#pragma unroll
    for (int m = 0; m < 4; ++m)
#pragma unroll
      for (int n = 0; n < 4; ++n)
        acc[m][n] = __builtin_amdgcn_mfma_f32_16x16x32_bf16(a[m], b[n], acc[m][n], 0, 0, 0);
  }

  const int r0 = (lane >> 4) * 4;
  const int cn = lane & 15;
#pragma unroll
  for (int n = 0; n < 4; ++n) {
    const int colg = bcol + wc * 64 + n * 16 + cn;
    const float bv = bias[colg];
#pragma unroll
    for (int m = 0; m < 4; ++m) {
      const int rowg = brow + wr * 64 + m * 16 + r0;
#pragma unroll
      for (int r = 0; r < 4; ++r) {
        const float v = acc[m][n][r] + bv;
        if (OUTF32)
          outF[(size_t)(rowg + r) * Ndim + colg] = v;
        else
          outB[(size_t)(rowg + r) * Ndim + colg] = f2bf(v);
      }
    }
  }
}

// =====================================================================
// V transpose: qkv v-part [b,h][n,d] -> vt [b,h][d,n]
// =====================================================================
__global__ __launch_bounds__(256) void transpose_v_kernel(const u16* __restrict__ qkv,
                                                          u16* __restrict__ vt) {
  __shared__ u16 t[64][72];
  const int tid = threadIdx.x;
  const int nt = blockIdx.x, h = blockIdx.y, b = blockIdx.z;
  const u16* src = qkv + (size_t)(b * 1024 + nt * 64) * 2304 + 1536 + h * 64;
#pragma unroll
  for (int j = 0; j < 2; ++j) {
    const int c = j * 256 + tid;
    const int row = c >> 3;
    const int off = (c & 7) * 8;
    *(bf16x8*)&t[row][off] = *(const bf16x8*)(src + (size_t)row * 2304 + off);
  }
  __syncthreads();
  u16* dst = vt + (size_t)(b * 12 + h) * 64 * 1024 + nt * 64;
#pragma unroll
  for (int j = 0; j < 2; ++j) {
    const int c = j * 256 + tid;
    const int drow = c >> 3;
    const int noff = (c & 7) * 8;
    bf16x8 o;
#pragma unroll
    for (int i = 0; i < 8; ++i) o[i] = (short)t[noff + i][drow];
    *(bf16x8*)(dst + (size_t)drow * 1024 + noff) = o;
  }
}

// =====================================================================
// Gather the 146 global columns (k%14 in {12,13}) into compact buffers:
//   kgc [b,h][192][64]   (rows 146..191 zero)
//   vgc [b,h][64][192]   (V^T layout, cols 146..191 zero)
// One block per (b,h).
// =====================================================================
__global__ __launch_bounds__(256) void gather_global_kernel(const u16* __restrict__ qkv,
                                                            u16* __restrict__ kgc,
                                                            u16* __restrict__ vgc) {
  __shared__ u16 tl[192][72];
  const int tid = threadIdx.x;
  const int h = blockIdx.x % 12;
  const int b = blockIdx.x / 12;
  const u16* Kg = qkv + (size_t)(b * 1024) * 2304 + 768 + h * 64;
  const u16* Vg = qkv + (size_t)(b * 1024) * 2304 + 1536 + h * 64;
  u16* kout = kgc + (size_t)blockIdx.x * 192 * 64;
  u16* vout = vgc + (size_t)blockIdx.x * 64 * 192;

  // K gather (and V rows into LDS): 192 rows x 8 chunks
  for (int t = tid; t < 1536; t += 256) {
    const int s = t >> 3, ch = t & 7;
    bf16x8 kv = {}, vv = {};
    if (s < 146) {
      const int tok = (s >> 1) * 14 + 12 + (s & 1);
      kv = *(const bf16x8*)(Kg + (size_t)tok * 2304 + ch * 8);
      vv = *(const bf16x8*)(Vg + (size_t)tok * 2304 + ch * 8);
    }
    *(bf16x8*)(kout + s * 64 + ch * 8) = kv;
    *(bf16x8*)&tl[s][ch * 8] = vv;
  }
  __syncthreads();
  // write V^T: [64 d][192 slots]
  for (int t = tid; t < 64 * 24; t += 256) {
    const int d = t / 24, c8 = (t % 24) * 8;
    bf16x8 o;
#pragma unroll
    for (int i = 0; i < 8; ++i) o[i] = (short)tl[c8 + i][d];
    *(bf16x8*)(vout + (size_t)d * 192 + c8) = o;
  }
}

// =====================================================================
// Masked flash attention, COMPACT column space.
// 5 k-tiles: it=0..2 global-compact (192 slots, 146 valid),
//            it=3..4 local contiguous token window (aligned, clamped).
// Grid (qt=16, h=12, b=16), 256 thr = 4 waves, 16 q rows/wave.
// =====================================================================
__global__ __launch_bounds__(256, 2) void attn_kernel(const u16* __restrict__ qkv,
                                                      const u16* __restrict__ vt,
                                                      const u16* __restrict__ kgc,
                                                      const u16* __restrict__ vgc,
                                                      u16* __restrict__ ao) {
  __shared__ u16 sQ[64 * 64];
  __shared__ u16 sK[64 * 64];
  __shared__ u16 sV[64 * 64];  // V^T tile: [d][k]
  __shared__ u16 sP[4][16 * 72];

  const int tid = threadIdx.x;
  const int lane = tid & 63;
  const int wid = tid >> 6;
  const int qt = blockIdx.x, h = blockIdx.y, b = blockIdx.z;
  const int q0 = qt * 64;
  const int colL = lane & 15;
  const int kgrp = lane >> 4;
  const int bh = b * 12 + h;

  const u16* Qg = qkv + (size_t)(b * 1024 + q0) * 2304 + h * 64;
  const u16* Kg = qkv + (size_t)(b * 1024) * 2304 + 768 + h * 64;
  const u16* Vt = vt + (size_t)bh * 64 * 1024;
  const u16* Kc = kgc + (size_t)bh * 192 * 64;
  const u16* Vc = vgc + (size_t)bh * 64 * 192;

  // local window: tokens [tok0a, tok0a+128), 8-aligned
  const int first_blk = q0 / 14;
  const int tok0a = (first_blk * 14) & ~7;

#pragma unroll
  for (int j = 0; j < 2; ++j) {
    const int c = j * 256 + tid;
    const int row = c >> 3;
    const int off = (c & 7) * 8;
    gload_lds16(Qg + (size_t)row * 2304 + off, &sQ[c * 8]);
  }
  __syncthreads();

  bf16x8 qf[2];
#pragma unroll
  for (int ks = 0; ks < 2; ++ks)
    qf[ks] = *(const bf16x8*)&sQ[(wid * 16 + colL) * 64 + ks * 32 + kgrp * 8];

  int qblk[4];
#pragma unroll
  for (int r = 0; r < 4; ++r) qblk[r] = (q0 + wid * 16 + kgrp * 4 + r) / 14;

  const float SCL = 0.125f * 1.44269504088896f;  // scale * log2(e)
  const float NEG = -3e38f;
  float mrun[4] = {NEG, NEG, NEG, NEG};
  float lsum[4] = {0.f, 0.f, 0.f, 0.f};
  f32x4 oacc[4] = {};

  for (int it = 0; it < 5; ++it) {
    __syncthreads();
    if (it < 3) {
#pragma unroll
      for (int j = 0; j < 2; ++j) {
        const int c = j * 256 + tid;
        const int row = c >> 3;
        const int sb = ((c & 7) * 16) ^ ((row & 7) << 4);
        gload_lds16((const char*)(Kc + (size_t)(it * 64 + row) * 64) + sb, &sK[c * 8]);
        gload_lds16((const char*)(Vc + (size_t)row * 192 + it * 64) + sb, &sV[c * 8]);
      }
    } else {
      const int tc0 = tok0a + (it - 3) * 64;
#pragma unroll
      for (int j = 0; j < 2; ++j) {
        const int c = j * 256 + tid;
        const int row = c >> 3;
        const int sb = ((c & 7) * 16) ^ ((row & 7) << 4);
        const int ktok = min(tc0 + row, 1023);
        gload_lds16((const char*)(Kg + (size_t)ktok * 2304) + sb, &sK[c * 8]);
        const int vb = min(tc0 * 2 + sb, 2032);  // clamp token chunk, keep 16B align
        gload_lds16((const char*)(Vt + (size_t)row * 1024) + vb, &sV[c * 8]);
      }
    }
    __syncthreads();

    // S = Q K^T
    f32x4 s[4] = {};
#pragma unroll
    for (int n = 0; n < 4; ++n) {
      const int row = n * 16 + colL;
#pragma unroll
      for (int ks = 0; ks < 2; ++ks) {
        const int cb = (ks * 32 + kgrp * 8) * 2;
        bf16x8 kf = *(const bf16x8*)((const char*)sK + row * 128 + (cb ^ ((row & 7) << 4)));
        s[n] = __builtin_amdgcn_mfma_f32_16x16x32_bf16(qf[ks], kf, s[n], 0, 0, 0);
      }
    }

    // mask + scale (log2 domain)
    float sv[4][4];
    if (it < 3) {
#pragma unroll
      for (int n = 0; n < 4; ++n) {
        const bool gv = (it * 64 + n * 16 + colL) < 146;
#pragma unroll
        for (int r = 0; r < 4; ++r) sv[n][r] = gv ? s[n][r] * SCL : NEG;
      }
    } else {
      const int tc0 = tok0a + (it - 3) * 64;
#pragma unroll
      for (int n = 0; n < 4; ++n) {
        const int t = tc0 + n * 16 + colL;
        const int tb = t / 14;
        const bool cv = (t < 1024) && ((t - tb * 14) < 12);
#pragma unroll
        for (int r = 0; r < 4; ++r) {
          const bool ok = cv && (tb == qblk[r]);
          sv[n][r] = ok ? s[n][r] * SCL : NEG;
        }
      }
    }

    float pmax[4];
#pragma unroll
    for (int r = 0; r < 4; ++r) {
      float v = fmaxf(fmaxf(sv[0][r], sv[1][r]), fmaxf(sv[2][r], sv[3][r]));
#pragma unroll
      for (int msk = 1; msk <= 8; msk <<= 1) v = fmaxf(v, __shfl_xor(v, msk));
      pmax[r] = v;
    }

    float corr[4], psum[4];
#pragma unroll
    for (int r = 0; r < 4; ++r) {
      const float mn = fmaxf(mrun[r], pmax[r]);
      corr[r] = exp2f(mrun[r] - mn);
      mrun[r] = mn;
      psum[r] = 0.f;
    }

    float p[4][4];
#pragma unroll
    for (int n = 0; n < 4; ++n)
#pragma unroll
      for (int r = 0; r < 4; ++r) {
        p[n][r] = exp2f(sv[n][r] - mrun[r]);
        psum[r] += p[n][r];
      }

#pragma unroll
    for (int r = 0; r < 4; ++r) {
      float v = psum[r];
#pragma unroll
      for (int msk = 1; msk <= 8; msk <<= 1) v += __shfl_xor(v, msk);
      lsum[r] = lsum[r] * corr[r] + v;
    }

    // P -> per-wave LDS (C-layout rows), then read back as A-frags
#pragma unroll
    for (int n = 0; n < 4; ++n)
#pragma unroll
      for (int r = 0; r < 4; ++r)
        sP[wid][(kgrp * 4 + r) * 72 + n * 16 + colL] = f2bf(p[n][r]);

#pragma unroll
    for (int dn = 0; dn < 4; ++dn)
#pragma unroll
      for (int r = 0; r < 4; ++r) oacc[dn][r] *= corr[r];

#pragma unroll
    for (int ks = 0; ks < 2; ++ks) {
      bf16x8 pf = *(const bf16x8*)&sP[wid][colL * 72 + ks * 32 + kgrp * 8];
#pragma unroll
      for (int dn = 0; dn < 4; ++dn) {
        const int vrow = dn * 16 + colL;
        const int cb = (ks * 32 + kgrp * 8) * 2;
        bf16x8 vf = *(const bf16x8*)((const char*)sV + vrow * 128 + (cb ^ ((vrow & 7) << 4)));
        oacc[dn] = __builtin_amdgcn_mfma_f32_16x16x32_bf16(pf, vf, oacc[dn], 0, 0, 0);
      }
    }
  }

  float inv[4];
#pragma unroll
  for (int r = 0; r < 4; ++r) inv[r] = 1.0f / lsum[r];
#pragma unroll
  for (int dn = 0; dn < 4; ++dn)
#pragma unroll
    for (int r = 0; r < 4; ++r) {
      const int rowg = b * 1024 + q0 + wid * 16 + kgrp * 4 + r;
      const int colg = h * 64 + dn * 16 + colL;
      ao[(size_t)rowg * 768 + colg] = f2bf(oacc[dn][r] * inv[r]);
    }
}

// =====================================================================
extern "C" void kernel_launch(void* const* d_in, const int* in_sizes, int n_in,
                              void* d_out, int out_size, void* d_ws, size_t ws_size,
                              hipStream_t stream) {
  const float* x = (const float*)d_in[0];
  const float* w_qkv = (const float*)d_in[1];
  const float* b_qkv = (const float*)d_in[2];
  const float* w_proj = (const float*)d_in[3];
  const float* b_proj = (const float*)d_in[4];
  float* out = (float*)d_out;

  char* ws = (char*)d_ws;
  size_t off = 0;
  auto alloc = [&](size_t bytes) {
    char* p = ws + off;
    off += (bytes + 255) & ~(size_t)255;
    return p;
  };
  u16* x_bf = (u16*)alloc(16384ull * 768 * 2);  // later reused as attention output
  u16* wq_bf = (u16*)alloc(2304ull * 768 * 2);
  u16* wp_bf = (u16*)alloc(768ull * 768 * 2);
  u16* qkvb = (u16*)alloc(16384ull * 2304 * 2);
  u16* vt = (u16*)alloc(192ull * 64 * 1024 * 2);
  u16* kgc = (u16*)alloc(192ull * 192 * 64 * 2);
  u16* vgc = (u16*)alloc(192ull * 64 * 192 * 2);
  u16* ao = x_bf;  // alias: x_bf dead after QKV GEMM

  cvt_split_kernel<<<dim3(4096), dim3(256), 0, stream>>>(x, x_bf, nullptr, 16384 * 768 / 4);
  cvt_split_kernel<<<dim3(1728), dim3(256), 0, stream>>>(w_qkv, wq_bf, nullptr, 2304 * 768 / 4);
  cvt_split_kernel<<<dim3(576), dim3(256), 0, stream>>>(w_proj, wp_bf, nullptr, 768 * 768 / 4);

  gemm_bt<0><<<dim3(128, 18), dim3(256), 0, stream>>>(x_bf, wq_bf, b_qkv,
                                                      nullptr, qkvb, 2304, 768);
  transpose_v_kernel<<<dim3(16, 12, 16), dim3(256), 0, stream>>>(qkvb, vt);
  gather_global_kernel<<<dim3(192), dim3(256), 0, stream>>>(qkvb, kgc, vgc);
  attn_kernel<<<dim3(16, 12, 16), dim3(256), 0, stream>>>(qkvb, vt, kgc, vgc, ao);
  gemm_bt<1><<<dim3(128, 6), dim3(256), 0, stream>>>(ao, wp_bf, b_proj,
                                                     out, nullptr, 768, 768);
}

// Round 7
// 200.635 us; speedup vs baseline: 1.0313x; 1.0313x over previous
//
#include <hip/hip_runtime.h>
#include <stdint.h>

typedef unsigned short u16;
typedef __attribute__((ext_vector_type(8))) short bf16x8;
typedef __attribute__((ext_vector_type(4))) short s16x4;
typedef __attribute__((ext_vector_type(4))) float f32x4;

// ---- bf16 helpers (manual RNE; no hip_bf16.h dependency) ----
__device__ __forceinline__ u16 f2bf(float f) {
  uint32_t x = __builtin_bit_cast(uint32_t, f);
  uint32_t r = (x + 0x7fffu + ((x >> 16) & 1u)) >> 16;
  return (u16)r;
}
__device__ __forceinline__ float bf2f(u16 u) {
  return __builtin_bit_cast(float, (uint32_t)u << 16);
}

// ---- async global -> LDS, 16B per lane ----
typedef __attribute__((address_space(3))) uint32_t lds_u32;
typedef const __attribute__((address_space(1))) uint32_t glb_u32;
__device__ __forceinline__ void gload_lds16(const void* g, void* l) {
  __builtin_amdgcn_global_load_lds(
      reinterpret_cast<glb_u32*>(reinterpret_cast<uintptr_t>(g)),
      reinterpret_cast<lds_u32*>(reinterpret_cast<uintptr_t>(l)),
      16, 0, 0);
}

// =====================================================================
// convert f32 -> bf16 (hi), optional residual (lo). 4 elems / thread.
// =====================================================================
__global__ void cvt_split_kernel(const float* __restrict__ in, u16* __restrict__ hi,
                                 u16* __restrict__ lo, int n4) {
  typedef __attribute__((ext_vector_type(4))) float float4v;
  int i = blockIdx.x * 256 + threadIdx.x;
  const int stride = gridDim.x * 256;
  for (; i < n4; i += stride) {
    float4v v = *(const float4v*)(in + (size_t)i * 4);
    s16x4 hv;
#pragma unroll
    for (int j = 0; j < 4; ++j) hv[j] = (short)f2bf(v[j]);
    *(s16x4*)(hi + (size_t)i * 4) = hv;
    if (lo) {
      s16x4 lv;
#pragma unroll
      for (int j = 0; j < 4; ++j) lv[j] = (short)f2bf(v[j] - bf2f((u16)hv[j]));
      *(s16x4*)(lo + (size_t)i * 4) = lv;
    }
  }
}

// =====================================================================
// GEMM: C[M,N] = A[M,K] * B[N,K]^T + bias
// 128x128 tile, BK=32, 4 waves (2x2), mfma 16x16x32 bf16.
// 2-phase prefetch: double-buffered LDS, stage(t+1) issued BEFORE the
// MFMAs of tile t, ONE barrier per K-step (drain overlaps compute).
// Natural block order (R4/R6: both XCD swizzles regressed/neutral).
// =====================================================================
template <int OUTF32>
__global__ __launch_bounds__(256, 2) void gemm_bt(
    const u16* __restrict__ A, const u16* __restrict__ B0,
    const float* __restrict__ bias, float* __restrict__ outF, u16* __restrict__ outB,
    int Ndim, int Kdim) {
  __shared__ u16 sA[2][128 * 32];
  __shared__ u16 sB[2][128 * 32];

  const int tid = threadIdx.x;
  const int lane = tid & 63;
  const int wr = (tid >> 6) >> 1;
  const int wc = (tid >> 6) & 1;
  const int brow = blockIdx.x * 128;
  const int bcol = blockIdx.y * 128;

  auto stage = [&](int buf, int k0) {
#pragma unroll
    for (int j = 0; j < 2; ++j) {
      const int c = j * 256 + tid;
      const int r = c >> 2;
      const int off = (c & 3) * 8;
      gload_lds16(A + (size_t)(brow + r) * Kdim + k0 + off, &sA[buf][c * 8]);
      gload_lds16(B0 + (size_t)(bcol + r) * Kdim + k0 + off, &sB[buf][c * 8]);
    }
  };

  f32x4 acc[4][4] = {};

  stage(0, 0);
  __syncthreads();

  const int nt = Kdim >> 5;
  for (int t = 0; t < nt; ++t) {
    const int cur = t & 1;
    if (t + 1 < nt) stage(cur ^ 1, (t + 1) << 5);

    bf16x8 a[4], b[4];
#pragma unroll
    for (int m = 0; m < 4; ++m)
      a[m] = *(const bf16x8*)&sA[cur][(wr * 64 + m * 16 + (lane & 15)) * 32 + (lane >> 4) * 8];
#pragma unroll
    for (int n = 0; n < 4; ++n)
      b[n] = *(const bf16x8*)&sB[cur][(wc * 64 + n * 16 + (lane & 15)) * 32 + (lane >> 4) * 8];
#pragma unroll
    for (int m = 0; m < 4; ++m)
#pragma unroll
      for (int n = 0; n < 4; ++n)
        acc[m][n] = __builtin_amdgcn_mfma_f32_16x16x32_bf16(a[m], b[n], acc[m][n], 0, 0, 0);

    __syncthreads();  // drains stage(t+1) (overlapped with MFMAs above)
  }

  const int r0 = (lane >> 4) * 4;
  const int cn = lane & 15;
#pragma unroll
  for (int n = 0; n < 4; ++n) {
    const int colg = bcol + wc * 64 + n * 16 + cn;
    const float bv = bias[colg];
#pragma unroll
    for (int m = 0; m < 4; ++m) {
      const int rowg = brow + wr * 64 + m * 16 + r0;
#pragma unroll
      for (int r = 0; r < 4; ++r) {
        const float v = acc[m][n][r] + bv;
        if (OUTF32)
          outF[(size_t)(rowg + r) * Ndim + colg] = v;
        else
          outB[(size_t)(rowg + r) * Ndim + colg] = f2bf(v);
      }
    }
  }
}

// =====================================================================
// V transpose: qkv v-part [b,h][n,d] -> vt [b,h][d,n]
// =====================================================================
__global__ __launch_bounds__(256) void transpose_v_kernel(const u16* __restrict__ qkv,
                                                          u16* __restrict__ vt) {
  __shared__ u16 t[64][72];
  const int tid = threadIdx.x;
  const int nt = blockIdx.x, h = blockIdx.y, b = blockIdx.z;
  const u16* src = qkv + (size_t)(b * 1024 + nt * 64) * 2304 + 1536 + h * 64;
#pragma unroll
  for (int j = 0; j < 2; ++j) {
    const int c = j * 256 + tid;
    const int row = c >> 3;
    const int off = (c & 7) * 8;
    *(bf16x8*)&t[row][off] = *(const bf16x8*)(src + (size_t)row * 2304 + off);
  }
  __syncthreads();
  u16* dst = vt + (size_t)(b * 12 + h) * 64 * 1024 + nt * 64;
#pragma unroll
  for (int j = 0; j < 2; ++j) {
    const int c = j * 256 + tid;
    const int drow = c >> 3;
    const int noff = (c & 7) * 8;
    bf16x8 o;
#pragma unroll
    for (int i = 0; i < 8; ++i) o[i] = (short)t[noff + i][drow];
    *(bf16x8*)(dst + (size_t)drow * 1024 + noff) = o;
  }
}

// =====================================================================
// Gather the 146 global columns (k%14 in {12,13}) into compact buffers:
//   kgc [b,h][192][64]   (rows 146..191 zero)
//   vgc [b,h][64][192]   (V^T layout, cols 146..191 zero)
// One block per (b,h).
// =====================================================================
__global__ __launch_bounds__(256) void gather_global_kernel(const u16* __restrict__ qkv,
                                                            u16* __restrict__ kgc,
                                                            u16* __restrict__ vgc) {
  __shared__ u16 tl[192][72];
  const int tid = threadIdx.x;
  const int h = blockIdx.x % 12;
  const int b = blockIdx.x / 12;
  const u16* Kg = qkv + (size_t)(b * 1024) * 2304 + 768 + h * 64;
  const u16* Vg = qkv + (size_t)(b * 1024) * 2304 + 1536 + h * 64;
  u16* kout = kgc + (size_t)blockIdx.x * 192 * 64;
  u16* vout = vgc + (size_t)blockIdx.x * 64 * 192;

  // K gather (and V rows into LDS): 192 rows x 8 chunks
  for (int t = tid; t < 1536; t += 256) {
    const int s = t >> 3, ch = t & 7;
    bf16x8 kv = {}, vv = {};
    if (s < 146) {
      const int tok = (s >> 1) * 14 + 12 + (s & 1);
      kv = *(const bf16x8*)(Kg + (size_t)tok * 2304 + ch * 8);
      vv = *(const bf16x8*)(Vg + (size_t)tok * 2304 + ch * 8);
    }
    *(bf16x8*)(kout + s * 64 + ch * 8) = kv;
    *(bf16x8*)&tl[s][ch * 8] = vv;
  }
  __syncthreads();
  // write V^T: [64 d][192 slots]
  for (int t = tid; t < 64 * 24; t += 256) {
    const int d = t / 24, c8 = (t % 24) * 8;
    bf16x8 o;
#pragma unroll
    for (int i = 0; i < 8; ++i) o[i] = (short)tl[c8 + i][d];
    *(bf16x8*)(vout + (size_t)d * 192 + c8) = o;
  }
}

// =====================================================================
// Masked flash attention, COMPACT column space, 2-phase K/V prefetch.
// 5 k-tiles: it=0..2 global-compact (192 slots, 146 valid),
//            it=3..4 local contiguous token window (aligned, clamped).
// Grid (qt=16, h=12, b=16), 256 thr = 4 waves, 16 q rows/wave.
// =====================================================================
__global__ __launch_bounds__(256, 2) void attn_kernel(const u16* __restrict__ qkv,
                                                      const u16* __restrict__ vt,
                                                      const u16* __restrict__ kgc,
                                                      const u16* __restrict__ vgc,
                                                      u16* __restrict__ ao) {
  __shared__ u16 sQ[64 * 64];
  __shared__ u16 sK[2][64 * 64];
  __shared__ u16 sV[2][64 * 64];  // V^T tile: [d][k]
  __shared__ u16 sP[4][16 * 72];

  const int tid = threadIdx.x;
  const int lane = tid & 63;
  const int wid = tid >> 6;
  const int qt = blockIdx.x, h = blockIdx.y, b = blockIdx.z;
  const int q0 = qt * 64;
  const int colL = lane & 15;
  const int kgrp = lane >> 4;
  const int bh = b * 12 + h;

  const u16* Qg = qkv + (size_t)(b * 1024 + q0) * 2304 + h * 64;
  const u16* Kg = qkv + (size_t)(b * 1024) * 2304 + 768 + h * 64;
  const u16* Vt = vt + (size_t)bh * 64 * 1024;
  const u16* Kc = kgc + (size_t)bh * 192 * 64;
  const u16* Vc = vgc + (size_t)bh * 64 * 192;

  // local window: tokens [tok0a, tok0a+128), 8-aligned
  const int first_blk = q0 / 14;
  const int tok0a = (first_blk * 14) & ~7;

  auto stage_kv = [&](int buf, int it) {
    if (it < 3) {
#pragma unroll
      for (int j = 0; j < 2; ++j) {
        const int c = j * 256 + tid;
        const int row = c >> 3;
        const int sb = ((c & 7) * 16) ^ ((row & 7) << 4);
        gload_lds16((const char*)(Kc + (size_t)(it * 64 + row) * 64) + sb, &sK[buf][c * 8]);
        gload_lds16((const char*)(Vc + (size_t)row * 192 + it * 64) + sb, &sV[buf][c * 8]);
      }
    } else {
      const int tc0 = tok0a + (it - 3) * 64;
#pragma unroll
      for (int j = 0; j < 2; ++j) {
        const int c = j * 256 + tid;
        const int row = c >> 3;
        const int sb = ((c & 7) * 16) ^ ((row & 7) << 4);
        const int ktok = min(tc0 + row, 1023);
        gload_lds16((const char*)(Kg + (size_t)ktok * 2304) + sb, &sK[buf][c * 8]);
        const int vb = min(tc0 * 2 + sb, 2032);  // clamp token chunk, keep 16B align
        gload_lds16((const char*)(Vt + (size_t)row * 1024) + vb, &sV[buf][c * 8]);
      }
    }
  };

  // prologue: Q + first K/V tile, one drain
#pragma unroll
  for (int j = 0; j < 2; ++j) {
    const int c = j * 256 + tid;
    const int row = c >> 3;
    const int off = (c & 7) * 8;
    gload_lds16(Qg + (size_t)row * 2304 + off, &sQ[c * 8]);
  }
  stage_kv(0, 0);
  __syncthreads();

  bf16x8 qf[2];
#pragma unroll
  for (int ks = 0; ks < 2; ++ks)
    qf[ks] = *(const bf16x8*)&sQ[(wid * 16 + colL) * 64 + ks * 32 + kgrp * 8];

  int qblk[4];
#pragma unroll
  for (int r = 0; r < 4; ++r) qblk[r] = (q0 + wid * 16 + kgrp * 4 + r) / 14;

  const float SCL = 0.125f * 1.44269504088896f;  // scale * log2(e)
  const float NEG = -3e38f;
  float mrun[4] = {NEG, NEG, NEG, NEG};
  float lsum[4] = {0.f, 0.f, 0.f, 0.f};
  f32x4 oacc[4] = {};

  for (int it = 0; it < 5; ++it) {
    const int cur = it & 1;
    if (it + 1 < 5) stage_kv(cur ^ 1, it + 1);

    // S = Q K^T
    f32x4 s[4] = {};
#pragma unroll
    for (int n = 0; n < 4; ++n) {
      const int row = n * 16 + colL;
#pragma unroll
      for (int ks = 0; ks < 2; ++ks) {
        const int cb = (ks * 32 + kgrp * 8) * 2;
        bf16x8 kf = *(const bf16x8*)((const char*)&sK[cur][0] + row * 128 + (cb ^ ((row & 7) << 4)));
        s[n] = __builtin_amdgcn_mfma_f32_16x16x32_bf16(qf[ks], kf, s[n], 0, 0, 0);
      }
    }

    // mask + scale (log2 domain)
    float sv[4][4];
    if (it < 3) {
#pragma unroll
      for (int n = 0; n < 4; ++n) {
        const bool gv = (it * 64 + n * 16 + colL) < 146;
#pragma unroll
        for (int r = 0; r < 4; ++r) sv[n][r] = gv ? s[n][r] * SCL : NEG;
      }
    } else {
      const int tc0 = tok0a + (it - 3) * 64;
#pragma unroll
      for (int n = 0; n < 4; ++n) {
        const int t = tc0 + n * 16 + colL;
        const int tb = t / 14;
        const bool cv = (t < 1024) && ((t - tb * 14) < 12);
#pragma unroll
        for (int r = 0; r < 4; ++r) {
          const bool ok = cv && (tb == qblk[r]);
          sv[n][r] = ok ? s[n][r] * SCL : NEG;
        }
      }
    }

    float pmax[4];
#pragma unroll
    for (int r = 0; r < 4; ++r) {
      float v = fmaxf(fmaxf(sv[0][r], sv[1][r]), fmaxf(sv[2][r], sv[3][r]));
#pragma unroll
      for (int msk = 1; msk <= 8; msk <<= 1) v = fmaxf(v, __shfl_xor(v, msk));
      pmax[r] = v;
    }

    float corr[4], psum[4];
#pragma unroll
    for (int r = 0; r < 4; ++r) {
      const float mn = fmaxf(mrun[r], pmax[r]);
      corr[r] = exp2f(mrun[r] - mn);
      mrun[r] = mn;
      psum[r] = 0.f;
    }

    float p[4][4];
#pragma unroll
    for (int n = 0; n < 4; ++n)
#pragma unroll
      for (int r = 0; r < 4; ++r) {
        p[n][r] = exp2f(sv[n][r] - mrun[r]);
        psum[r] += p[n][r];
      }

#pragma unroll
    for (int r = 0; r < 4; ++r) {
      float v = psum[r];
#pragma unroll
      for (int msk = 1; msk <= 8; msk <<= 1) v += __shfl_xor(v, msk);
      lsum[r] = lsum[r] * corr[r] + v;
    }

    // P -> per-wave LDS (C-layout rows), then read back as A-frags
#pragma unroll
    for (int n = 0; n < 4; ++n)
#pragma unroll
      for (int r = 0; r < 4; ++r)
        sP[wid][(kgrp * 4 + r) * 72 + n * 16 + colL] = f2bf(p[n][r]);

#pragma unroll
    for (int dn = 0; dn < 4; ++dn)
#pragma unroll
      for (int r = 0; r < 4; ++r) oacc[dn][r] *= corr[r];

#pragma unroll
    for (int ks = 0; ks < 2; ++ks) {
      bf16x8 pf = *(const bf16x8*)&sP[wid][colL * 72 + ks * 32 + kgrp * 8];
#pragma unroll
      for (int dn = 0; dn < 4; ++dn) {
        const int vrow = dn * 16 + colL;
        const int cb = (ks * 32 + kgrp * 8) * 2;
        bf16x8 vf = *(const bf16x8*)((const char*)&sV[cur][0] + vrow * 128 + (cb ^ ((vrow & 7) << 4)));
        oacc[dn] = __builtin_amdgcn_mfma_f32_16x16x32_bf16(pf, vf, oacc[dn], 0, 0, 0);
      }
    }

    __syncthreads();  // drains stage_kv(it+1) (overlapped with compute above)
  }

  float inv[4];
#pragma unroll
  for (int r = 0; r < 4; ++r) inv[r] = 1.0f / lsum[r];
#pragma unroll
  for (int dn = 0; dn < 4; ++dn)
#pragma unroll
    for (int r = 0; r < 4; ++r) {
      const int rowg = b * 1024 + q0 + wid * 16 + kgrp * 4 + r;
      const int colg = h * 64 + dn * 16 + colL;
      ao[(size_t)rowg * 768 + colg] = f2bf(oacc[dn][r] * inv[r]);
    }
}

// =====================================================================
extern "C" void kernel_launch(void* const* d_in, const int* in_sizes, int n_in,
                              void* d_out, int out_size, void* d_ws, size_t ws_size,
                              hipStream_t stream) {
  const float* x = (const float*)d_in[0];
  const float* w_qkv = (const float*)d_in[1];
  const float* b_qkv = (const float*)d_in[2];
  const float* w_proj = (const float*)d_in[3];
  const float* b_proj = (const float*)d_in[4];
  float* out = (float*)d_out;

  char* ws = (char*)d_ws;
  size_t off = 0;
  auto alloc = [&](size_t bytes) {
    char* p = ws + off;
    off += (bytes + 255) & ~(size_t)255;
    return p;
  };
  u16* x_bf = (u16*)alloc(16384ull * 768 * 2);  // later reused as attention output
  u16* wq_bf = (u16*)alloc(2304ull * 768 * 2);
  u16* wp_bf = (u16*)alloc(768ull * 768 * 2);
  u16* qkvb = (u16*)alloc(16384ull * 2304 * 2);
  u16* vt = (u16*)alloc(192ull * 64 * 1024 * 2);
  u16* kgc = (u16*)alloc(192ull * 192 * 64 * 2);
  u16* vgc = (u16*)alloc(192ull * 64 * 192 * 2);
  u16* ao = x_bf;  // alias: x_bf dead after QKV GEMM

  cvt_split_kernel<<<dim3(4096), dim3(256), 0, stream>>>(x, x_bf, nullptr, 16384 * 768 / 4);
  cvt_split_kernel<<<dim3(1728), dim3(256), 0, stream>>>(w_qkv, wq_bf, nullptr, 2304 * 768 / 4);
  cvt_split_kernel<<<dim3(576), dim3(256), 0, stream>>>(w_proj, wp_bf, nullptr, 768 * 768 / 4);

  gemm_bt<0><<<dim3(128, 18), dim3(256), 0, stream>>>(x_bf, wq_bf, b_qkv,
                                                      nullptr, qkvb, 2304, 768);
  transpose_v_kernel<<<dim3(16, 12, 16), dim3(256), 0, stream>>>(qkvb, vt);
  gather_global_kernel<<<dim3(192), dim3(256), 0, stream>>>(qkvb, kgc, vgc);
  attn_kernel<<<dim3(16, 12, 16), dim3(256), 0, stream>>>(qkvb, vt, kgc, vgc, ao);
  gemm_bt<1><<<dim3(128, 6), dim3(256), 0, stream>>>(ao, wp_bf, b_proj,
                                                     out, nullptr, 768, 768);
}